// Round 1
// baseline (1319.363 us; speedup 1.0000x reference)
//
#include <hip/hip_runtime.h>

// GGCNConv: N=50000 nodes, E=1600000 edges, D=64
// ws layout (floats): g0[N*64] g1[N*64] srcL[N*64] dstL[N*64] agg[N*64] stats[512]
// d_out: node_out[N*64] then edge_out[E*64]; m staged in edge_out region.

// Swizzled LDS addressing for a 64x64 f32 tile (per-wave, 16KB):
// logical (row r, word c) -> r*64 + (((c>>1)+r)&31)*2 + (c&1)
// gives conflict-free-ish access for row-major writes AND column reads.

__global__ __launch_bounds__(256, 2) void node_kernel(
    const float* __restrict__ x,
    const float* __restrict__ Wg,   // Wg0 = Wg, Wg1 = Wg + 4096
    const float* __restrict__ Ws, const float* __restrict__ bs,
    const float* __restrict__ Wd, const float* __restrict__ bd,
    float* __restrict__ g0, float* __restrict__ g1,
    float* __restrict__ srcL, float* __restrict__ dstL,
    int N, int ntiles)
{
    __shared__ float ldsA[4][4096];
    const int lane = threadIdx.x & 63;
    const int wid  = threadIdx.x >> 6;
    float* lds = ldsA[wid];
    const int nw = gridDim.x * 4;
    const float bsv = bs[lane], bdv = bd[lane];

    for (int tile = blockIdx.x * 4 + wid; tile < ntiles; tile += nw) {
        const int r0 = tile * 64;
        // phase 1: stage 64 x-rows (clamped) into LDS, swizzled
        {
            const int rb = lane >> 5, c2 = lane & 31;
            #pragma unroll
            for (int i = 0; i < 32; ++i) {
                int r = 2 * i + rb;
                int row = r0 + r; if (row >= N) row = N - 1;
                float2 v = *reinterpret_cast<const float2*>(x + (size_t)row * 64 + 2 * c2);
                int p = ((c2 + r) & 31) << 1;
                *reinterpret_cast<float2*>(&lds[r * 64 + p]) = v;
            }
        }
        // phase 1.5: each thread pulls its own row into registers
        float xr[64];
        #pragma unroll
        for (int kk = 0; kk < 32; ++kk) {
            int p = ((kk + lane) & 31) << 1;
            float2 v = *reinterpret_cast<const float2*>(&lds[lane * 64 + p]);
            xr[2 * kk] = v.x; xr[2 * kk + 1] = v.y;
        }
        #pragma unroll 1
        for (int mt = 0; mt < 4; ++mt) {
            const float* __restrict__ Wm = (mt == 0) ? Wg : (mt == 1) ? (Wg + 4096)
                                         : (mt == 2) ? Ws : Wd;
            #pragma unroll 1
            for (int ct = 0; ct < 2; ++ct) {
                float acc[32];
                #pragma unroll
                for (int c = 0; c < 32; ++c) acc[c] = 0.f;
                const float* __restrict__ Wp = Wm + ct * 32;
                #pragma unroll
                for (int k = 0; k < 64; ++k) {
                    float a = xr[k];
                    #pragma unroll
                    for (int c = 0; c < 32; ++c)
                        acc[c] = fmaf(a, Wp[k * 64 + c], acc[c]);   // Wp idx wave-uniform -> s_load
                }
                #pragma unroll
                for (int cc = 0; cc < 16; ++cc) {
                    int q = ct * 16 + cc;
                    int p = ((q + lane) & 31) << 1;
                    *reinterpret_cast<float2*>(&lds[lane * 64 + p]) =
                        make_float2(acc[2 * cc], acc[2 * cc + 1]);
                }
            }
            float bv = (mt == 2) ? bsv : (mt == 3) ? bdv : 0.f;
            float* __restrict__ op = (mt == 0) ? g0 : (mt == 1) ? g1 : (mt == 2) ? srcL : dstL;
            for (int j = 0; j < 64; ++j) {
                int row = r0 + j;
                if (row >= N) break;
                int p = ((((lane >> 1) + j) & 31) << 1) | (lane & 1);
                op[(size_t)row * 64 + lane] = lds[j * 64 + p] + bv;
            }
        }
    }
}

__global__ __launch_bounds__(256, 2) void edge_kernel(
    const float* __restrict__ ea, const int* __restrict__ eidx,
    const float* __restrict__ W2, const float* __restrict__ bg,
    const float* __restrict__ g0, const float* __restrict__ g1,
    const float* __restrict__ dstL, float* __restrict__ m_out,
    float* __restrict__ agg, float* __restrict__ stats,
    int E, int ntiles)
{
    __shared__ float ldsA[4][4096];
    const int lane = threadIdx.x & 63;
    const int wid  = threadIdx.x >> 6;
    float* lds = ldsA[wid];
    const int nw = gridDim.x * 4;
    const float bgv = bg[lane];
    float ssum = 0.f, ssq = 0.f;

    for (int tile = blockIdx.x * 4 + wid; tile < ntiles; tile += nw) {
        const long e0 = (long)tile * 64;
        long el = e0 + lane; if (el >= E) el = E - 1;
        const int sv = eidx[el];
        const int dv = eidx[(long)E + el];

        // phase 1: stage 64 edge_attr rows into LDS (swizzled)
        {
            const int rb = lane >> 5, c2 = lane & 31;
            #pragma unroll
            for (int i = 0; i < 32; ++i) {
                int r = 2 * i + rb;
                long erow = e0 + r; if (erow >= E) erow = E - 1;
                float2 v = *reinterpret_cast<const float2*>(ea + erow * 64 + 2 * c2);
                int p = ((c2 + r) & 31) << 1;
                *reinterpret_cast<float2*>(&lds[r * 64 + p]) = v;
            }
        }
        // phase 1.5: thread t owns edge e0+t; pull its ea row into 64 VGPRs
        float ear[64];
        #pragma unroll
        for (int kk = 0; kk < 32; ++kk) {
            int p = ((kk + lane) & 31) << 1;
            float2 v = *reinterpret_cast<const float2*>(&lds[lane * 64 + p]);
            ear[2 * kk] = v.x; ear[2 * kk + 1] = v.y;
        }
        // phase 2/3: m_partial = ea @ Wg2, in two 32-column halves; transpose via LDS
        #pragma unroll 1
        for (int ct = 0; ct < 2; ++ct) {
            float acc[32];
            #pragma unroll
            for (int c = 0; c < 32; ++c) acc[c] = 0.f;
            const float* __restrict__ Wp = W2 + ct * 32;
            #pragma unroll
            for (int k = 0; k < 64; ++k) {
                float a = ear[k];
                #pragma unroll
                for (int c = 0; c < 32; ++c)
                    acc[c] = fmaf(a, Wp[k * 64 + c], acc[c]);   // wave-uniform -> s_load
            }
            #pragma unroll
            for (int cc = 0; cc < 16; ++cc) {
                int q = ct * 16 + cc;
                int p = ((q + lane) & 31) << 1;
                *reinterpret_cast<float2*>(&lds[lane * 64 + p]) =
                    make_float2(acc[2 * cc], acc[2 * cc + 1]);
            }
        }
        // phase 4: epilogue, wave-per-edge (lane = column) — all global ops coalesced
        long rem = (long)E - e0;
        int jmax = rem < 64 ? (int)rem : 64;
        for (int j = 0; j < jmax; ++j) {
            int p = ((((lane >> 1) + j) & 31) << 1) | (lane & 1);
            float mv = lds[j * 64 + p];
            int s = __shfl(sv, j, 64);
            int d = __shfl(dv, j, 64);
            mv += bgv + g0[(size_t)s * 64 + lane] + g1[(size_t)d * 64 + lane];
            m_out[(e0 + j) * 64 + lane] = mv;
            ssum += mv;
            ssq = fmaf(mv, mv, ssq);
            float sg = __fdividef(1.f, 1.f + __expf(mv * -0.125f));
            float dl = dstL[(size_t)d * 64 + lane];
            atomicAdd(&agg[(size_t)s * 64 + lane], sg * dl);
        }
    }
    atomicAdd(&stats[lane], ssum);
    atomicAdd(&stats[64 + lane], ssq);
}

__global__ void node_stats_kernel(const float* __restrict__ srcL, const float* __restrict__ agg,
                                  float* __restrict__ stats, int N)
{
    const int lane = threadIdx.x & 63;
    const int wid  = threadIdx.x >> 6;
    const int w = blockIdx.x * 4 + wid, nw = gridDim.x * 4;
    float s = 0.f, q = 0.f;
    for (int row = w; row < N; row += nw) {
        float h = srcL[(size_t)row * 64 + lane] + agg[(size_t)row * 64 + lane];
        s += h; q = fmaf(h, h, q);
    }
    atomicAdd(&stats[128 + lane], s);
    atomicAdd(&stats[192 + lane], q);
}

__global__ void finalize_kernel(float* __restrict__ stats,
                                const float* __restrict__ gn, const float* __restrict__ bn,
                                const float* __restrict__ ge, const float* __restrict__ be,
                                float invE, float invN)
{
    int c = threadIdx.x;  // 64 threads
    float mu = stats[c] * invE;
    float var = stats[64 + c] * invE - mu * mu;
    float rs = rsqrtf(var + 1e-5f);
    float sc = rs * ge[c];
    stats[256 + c] = sc;
    stats[320 + c] = be[c] - mu * sc;
    mu = stats[128 + c] * invN;
    var = stats[192 + c] * invN - mu * mu;
    rs = rsqrtf(var + 1e-5f);
    sc = rs * gn[c];
    stats[384 + c] = sc;
    stats[448 + c] = bn[c] - mu * sc;
}

__global__ void edge_norm_kernel(float* __restrict__ mbuf, const float* __restrict__ stats, long n4)
{
    long i = (long)blockIdx.x * blockDim.x + threadIdx.x;
    const long stride = (long)gridDim.x * blockDim.x;  // multiple of 16
    int c4 = (int)(i & 15) * 4;
    float4 sc = *reinterpret_cast<const float4*>(&stats[256 + c4]);
    float4 sh = *reinterpret_cast<const float4*>(&stats[320 + c4]);
    float4* p = reinterpret_cast<float4*>(mbuf);
    for (; i < n4; i += stride) {
        float4 v = p[i];
        v.x = fmaxf(fmaf(v.x, sc.x, sh.x), 0.f);
        v.y = fmaxf(fmaf(v.y, sc.y, sh.y), 0.f);
        v.z = fmaxf(fmaf(v.z, sc.z, sh.z), 0.f);
        v.w = fmaxf(fmaf(v.w, sc.w, sh.w), 0.f);
        p[i] = v;
    }
}

__global__ void node_norm_kernel(const float* __restrict__ srcL, const float* __restrict__ agg,
                                 const float* __restrict__ stats, float* __restrict__ out, long n4)
{
    long i = (long)blockIdx.x * blockDim.x + threadIdx.x;
    const long stride = (long)gridDim.x * blockDim.x;  // multiple of 16
    int c4 = (int)(i & 15) * 4;
    float4 sc = *reinterpret_cast<const float4*>(&stats[384 + c4]);
    float4 sh = *reinterpret_cast<const float4*>(&stats[448 + c4]);
    const float4* a = reinterpret_cast<const float4*>(srcL);
    const float4* b = reinterpret_cast<const float4*>(agg);
    float4* o = reinterpret_cast<float4*>(out);
    for (; i < n4; i += stride) {
        float4 va = a[i], vb = b[i];
        float4 v;
        v.x = fmaxf(fmaf(va.x + vb.x, sc.x, sh.x), 0.f);
        v.y = fmaxf(fmaf(va.y + vb.y, sc.y, sh.y), 0.f);
        v.z = fmaxf(fmaf(va.z + vb.z, sc.z, sh.z), 0.f);
        v.w = fmaxf(fmaf(va.w + vb.w, sc.w, sh.w), 0.f);
        o[i] = v;
    }
}

extern "C" void kernel_launch(void* const* d_in, const int* in_sizes, int n_in,
                              void* d_out, int out_size, void* d_ws, size_t ws_size,
                              hipStream_t stream)
{
    const float* x    = (const float*)d_in[0];
    const int*   eidx = (const int*)d_in[1];
    const float* ea   = (const float*)d_in[2];
    const float* Wg   = (const float*)d_in[3];
    const float* bg   = (const float*)d_in[4];
    const float* Ws   = (const float*)d_in[5];
    const float* bs   = (const float*)d_in[6];
    const float* Wd   = (const float*)d_in[7];
    const float* bd   = (const float*)d_in[8];
    const float* gn   = (const float*)d_in[9];
    const float* bn   = (const float*)d_in[10];
    const float* ge   = (const float*)d_in[11];
    const float* be   = (const float*)d_in[12];

    const int N = in_sizes[0] / 64;
    const int E = in_sizes[2] / 64;

    float* ws    = (float*)d_ws;
    size_t nb    = (size_t)N * 64;
    float* g0    = ws;
    float* g1    = ws + nb;
    float* srcL  = ws + 2 * nb;
    float* dstL  = ws + 3 * nb;
    float* agg   = ws + 4 * nb;
    float* stats = ws + 5 * nb;

    float* node_out = (float*)d_out;
    float* m_out    = node_out + nb;   // stage m in edge_out region, normalize in place

    hipMemsetAsync(agg, 0, nb * sizeof(float), stream);
    hipMemsetAsync(stats, 0, 512 * sizeof(float), stream);

    const int ntilesN = (N + 63) / 64;
    node_kernel<<<196, 256, 0, stream>>>(x, Wg, Ws, bs, Wd, bd, g0, g1, srcL, dstL, N, ntilesN);

    const int ntilesE = (E + 63) / 64;
    edge_kernel<<<1568, 256, 0, stream>>>(ea, eidx, Wg + 128 * 64, bg, g0, g1, dstL,
                                          m_out, agg, stats, E, ntilesE);

    node_stats_kernel<<<256, 256, 0, stream>>>(srcL, agg, stats, N);
    finalize_kernel<<<1, 64, 0, stream>>>(stats, gn, bn, ge, be, 1.f / (float)E, 1.f / (float)N);

    edge_norm_kernel<<<4096, 256, 0, stream>>>(m_out, stats, (long)E * 16);
    node_norm_kernel<<<1024, 256, 0, stream>>>(srcL, agg, stats, node_out, (long)N * 16);
}

// Round 2
// 1279.006 us; speedup vs baseline: 1.0316x; 1.0316x over previous
//
#include <hip/hip_runtime.h>

// GGCNConv: N=50000 nodes, E=1600000 edges, D=64
// ws layout (floats): g0[N*64] g1[N*64] srcL[N*64] dstL[N*64] agg[N*64] stats[512]
// d_out: node_out[N*64] then edge_out[E*64]; m staged in edge_out region.

// Swizzled LDS addressing for a 64x64 f32 tile (16KB):
// logical (row r, word c) -> r*64 + (((c>>1)+r)&31)*2 + (c&1)

__global__ __launch_bounds__(256, 2) void node_kernel(
    const float* __restrict__ x,
    const float* __restrict__ Wg,   // Wg0 = Wg, Wg1 = Wg + 4096
    const float* __restrict__ Ws, const float* __restrict__ bs,
    const float* __restrict__ Wd, const float* __restrict__ bd,
    float* __restrict__ g0, float* __restrict__ g1,
    float* __restrict__ srcL, float* __restrict__ dstL,
    int N, int ntiles)
{
    __shared__ float ldsA[4][4096];
    const int lane = threadIdx.x & 63;
    const int wid  = threadIdx.x >> 6;
    float* lds = ldsA[wid];
    const int nw = gridDim.x * 4;
    const float bsv = bs[lane], bdv = bd[lane];

    for (int tile = blockIdx.x * 4 + wid; tile < ntiles; tile += nw) {
        const int r0 = tile * 64;
        {
            const int rb = lane >> 5, c2 = lane & 31;
            #pragma unroll
            for (int i = 0; i < 32; ++i) {
                int r = 2 * i + rb;
                int row = r0 + r; if (row >= N) row = N - 1;
                float2 v = *reinterpret_cast<const float2*>(x + (size_t)row * 64 + 2 * c2);
                int p = ((c2 + r) & 31) << 1;
                *reinterpret_cast<float2*>(&lds[r * 64 + p]) = v;
            }
        }
        float xr[64];
        #pragma unroll
        for (int kk = 0; kk < 32; ++kk) {
            int p = ((kk + lane) & 31) << 1;
            float2 v = *reinterpret_cast<const float2*>(&lds[lane * 64 + p]);
            xr[2 * kk] = v.x; xr[2 * kk + 1] = v.y;
        }
        #pragma unroll 1
        for (int mt = 0; mt < 4; ++mt) {
            const float* __restrict__ Wm = (mt == 0) ? Wg : (mt == 1) ? (Wg + 4096)
                                         : (mt == 2) ? Ws : Wd;
            #pragma unroll 1
            for (int ct = 0; ct < 2; ++ct) {
                float acc[32];
                #pragma unroll
                for (int c = 0; c < 32; ++c) acc[c] = 0.f;
                const float* __restrict__ Wp = Wm + ct * 32;
                #pragma unroll
                for (int k = 0; k < 64; ++k) {
                    float a = xr[k];
                    #pragma unroll
                    for (int c = 0; c < 32; ++c)
                        acc[c] = fmaf(a, Wp[k * 64 + c], acc[c]);
                }
                #pragma unroll
                for (int cc = 0; cc < 16; ++cc) {
                    int q = ct * 16 + cc;
                    int p = ((q + lane) & 31) << 1;
                    *reinterpret_cast<float2*>(&lds[lane * 64 + p]) =
                        make_float2(acc[2 * cc], acc[2 * cc + 1]);
                }
            }
            float bv = (mt == 2) ? bsv : (mt == 3) ? bdv : 0.f;
            float* __restrict__ op = (mt == 0) ? g0 : (mt == 1) ? g1 : (mt == 2) ? srcL : dstL;
            for (int j = 0; j < 64; ++j) {
                int row = r0 + j;
                if (row >= N) break;
                int p = ((((lane >> 1) + j) & 31) << 1) | (lane & 1);
                op[(size_t)row * 64 + lane] = lds[j * 64 + p] + bv;
            }
        }
    }
}

// Block-cooperative edge kernel: one 64x64 tile per 256-thread block.
// 16KB LDS/block; each wave computes a 16-column slice; epilogue split 4-way.
__global__ __launch_bounds__(256, 4) void edge_kernel(
    const float* __restrict__ ea, const int* __restrict__ eidx,
    const float* __restrict__ W2, const float* __restrict__ bg,
    const float* __restrict__ g0, const float* __restrict__ g1,
    const float* __restrict__ dstL, float* __restrict__ m_out,
    float* __restrict__ agg, float* __restrict__ stats,
    int E, int ntiles)
{
    __shared__ float lds[4096];
    const int tid  = threadIdx.x;
    const int lane = tid & 63;
    const int wid  = __builtin_amdgcn_readfirstlane(tid >> 6);  // wave-uniform in SGPR
    const float bgv = bg[lane];
    float ssum = 0.f, ssq = 0.f;

    for (int tile = blockIdx.x; tile < ntiles; tile += gridDim.x) {
        const long e0 = (long)tile * 64;
        // phase 1: 256 threads cooperatively stage 64 ea rows into LDS (swizzled)
        #pragma unroll
        for (int j = 0; j < 8; ++j) {
            int fp = tid + j * 256;           // float2-pair index 0..2047
            int row = fp >> 5, c2 = fp & 31;  // 32 consecutive lanes -> one row, coalesced
            long erow = e0 + row; if (erow >= E) erow = E - 1;
            float2 v = *reinterpret_cast<const float2*>(ea + erow * 64 + 2 * c2);
            int p = ((c2 + row) & 31) << 1;
            *reinterpret_cast<float2*>(&lds[row * 64 + p]) = v;
        }
        __syncthreads();
        // phase 1.5: every thread pulls row `lane` (its edge) into registers
        float ear[64];
        #pragma unroll
        for (int kk = 0; kk < 32; ++kk) {
            int p = ((kk + lane) & 31) << 1;
            float2 v = *reinterpret_cast<const float2*>(&lds[lane * 64 + p]);
            ear[2 * kk] = v.x; ear[2 * kk + 1] = v.y;
        }
        __syncthreads();   // all ea reads done before m overwrites the tile
        // phase 2: wave `wid` computes columns [wid*16, wid*16+16) for its edge
        {
            float acc[16];
            #pragma unroll
            for (int c = 0; c < 16; ++c) acc[c] = 0.f;
            const float* __restrict__ Wp = W2 + wid * 16;
            #pragma unroll
            for (int k = 0; k < 64; ++k) {
                float a = ear[k];
                #pragma unroll
                for (int c = 0; c < 16; ++c)
                    acc[c] = fmaf(a, Wp[k * 64 + c], acc[c]);   // Wp idx wave-uniform -> s_load
            }
            #pragma unroll
            for (int cc = 0; cc < 8; ++cc) {
                int q = wid * 8 + cc;
                int p = ((q + lane) & 31) << 1;
                *reinterpret_cast<float2*>(&lds[lane * 64 + p]) =
                    make_float2(acc[2 * cc], acc[2 * cc + 1]);
            }
        }
        __syncthreads();
        // phase 3: epilogue; wave `wid` handles edges j = wid*16 .. +15, lane = column
        #pragma unroll 4
        for (int i = 0; i < 16; ++i) {
            int j = wid * 16 + i;        // wave-uniform (wid is SGPR)
            long e = e0 + j;
            if (e >= E) break;
            int s = eidx[e];             // uniform address -> s_load
            int d = eidx[(long)E + e];
            int p = ((((lane >> 1) + j) & 31) << 1) | (lane & 1);
            float mv = lds[j * 64 + p];
            mv += bgv + g0[(size_t)s * 64 + lane] + g1[(size_t)d * 64 + lane];
            m_out[e * 64 + lane] = mv;
            ssum += mv;
            ssq = fmaf(mv, mv, ssq);
            float sg = __fdividef(1.f, 1.f + __expf(mv * -0.125f));
            atomicAdd(&agg[(size_t)s * 64 + lane], sg * dstL[(size_t)d * 64 + lane]);
        }
        __syncthreads();   // epilogue LDS reads done before next tile's staging
    }
    atomicAdd(&stats[lane], ssum);
    atomicAdd(&stats[64 + lane], ssq);
}

__global__ void node_stats_kernel(const float* __restrict__ srcL, const float* __restrict__ agg,
                                  float* __restrict__ stats, int N)
{
    const int lane = threadIdx.x & 63;
    const int wid  = threadIdx.x >> 6;
    const int w = blockIdx.x * 4 + wid, nw = gridDim.x * 4;
    float s = 0.f, q = 0.f;
    for (int row = w; row < N; row += nw) {
        float h = srcL[(size_t)row * 64 + lane] + agg[(size_t)row * 64 + lane];
        s += h; q = fmaf(h, h, q);
    }
    atomicAdd(&stats[128 + lane], s);
    atomicAdd(&stats[192 + lane], q);
}

__global__ void finalize_kernel(float* __restrict__ stats,
                                const float* __restrict__ gn, const float* __restrict__ bn,
                                const float* __restrict__ ge, const float* __restrict__ be,
                                float invE, float invN)
{
    int c = threadIdx.x;  // 64 threads
    float mu = stats[c] * invE;
    float var = stats[64 + c] * invE - mu * mu;
    float rs = rsqrtf(var + 1e-5f);
    float sc = rs * ge[c];
    stats[256 + c] = sc;
    stats[320 + c] = be[c] - mu * sc;
    mu = stats[128 + c] * invN;
    var = stats[192 + c] * invN - mu * mu;
    rs = rsqrtf(var + 1e-5f);
    sc = rs * gn[c];
    stats[384 + c] = sc;
    stats[448 + c] = bn[c] - mu * sc;
}

__global__ void edge_norm_kernel(float* __restrict__ mbuf, const float* __restrict__ stats, long n4)
{
    long i = (long)blockIdx.x * blockDim.x + threadIdx.x;
    const long stride = (long)gridDim.x * blockDim.x;  // multiple of 16
    int c4 = (int)(i & 15) * 4;
    float4 sc = *reinterpret_cast<const float4*>(&stats[256 + c4]);
    float4 sh = *reinterpret_cast<const float4*>(&stats[320 + c4]);
    float4* p = reinterpret_cast<float4*>(mbuf);
    for (; i < n4; i += stride) {
        float4 v = p[i];
        v.x = fmaxf(fmaf(v.x, sc.x, sh.x), 0.f);
        v.y = fmaxf(fmaf(v.y, sc.y, sh.y), 0.f);
        v.z = fmaxf(fmaf(v.z, sc.z, sh.z), 0.f);
        v.w = fmaxf(fmaf(v.w, sc.w, sh.w), 0.f);
        p[i] = v;
    }
}

__global__ void node_norm_kernel(const float* __restrict__ srcL, const float* __restrict__ agg,
                                 const float* __restrict__ stats, float* __restrict__ out, long n4)
{
    long i = (long)blockIdx.x * blockDim.x + threadIdx.x;
    const long stride = (long)gridDim.x * blockDim.x;  // multiple of 16
    int c4 = (int)(i & 15) * 4;
    float4 sc = *reinterpret_cast<const float4*>(&stats[384 + c4]);
    float4 sh = *reinterpret_cast<const float4*>(&stats[448 + c4]);
    const float4* a = reinterpret_cast<const float4*>(srcL);
    const float4* b = reinterpret_cast<const float4*>(agg);
    float4* o = reinterpret_cast<float4*>(out);
    for (; i < n4; i += stride) {
        float4 va = a[i], vb = b[i];
        float4 v;
        v.x = fmaxf(fmaf(va.x + vb.x, sc.x, sh.x), 0.f);
        v.y = fmaxf(fmaf(va.y + vb.y, sc.y, sh.y), 0.f);
        v.z = fmaxf(fmaf(va.z + vb.z, sc.z, sh.z), 0.f);
        v.w = fmaxf(fmaf(va.w + vb.w, sc.w, sh.w), 0.f);
        o[i] = v;
    }
}

extern "C" void kernel_launch(void* const* d_in, const int* in_sizes, int n_in,
                              void* d_out, int out_size, void* d_ws, size_t ws_size,
                              hipStream_t stream)
{
    const float* x    = (const float*)d_in[0];
    const int*   eidx = (const int*)d_in[1];
    const float* ea   = (const float*)d_in[2];
    const float* Wg   = (const float*)d_in[3];
    const float* bg   = (const float*)d_in[4];
    const float* Ws   = (const float*)d_in[5];
    const float* bs   = (const float*)d_in[6];
    const float* Wd   = (const float*)d_in[7];
    const float* bd   = (const float*)d_in[8];
    const float* gn   = (const float*)d_in[9];
    const float* bn   = (const float*)d_in[10];
    const float* ge   = (const float*)d_in[11];
    const float* be   = (const float*)d_in[12];

    const int N = in_sizes[0] / 64;
    const int E = in_sizes[2] / 64;

    float* ws    = (float*)d_ws;
    size_t nb    = (size_t)N * 64;
    float* g0    = ws;
    float* g1    = ws + nb;
    float* srcL  = ws + 2 * nb;
    float* dstL  = ws + 3 * nb;
    float* agg   = ws + 4 * nb;
    float* stats = ws + 5 * nb;

    float* node_out = (float*)d_out;
    float* m_out    = node_out + nb;   // stage m in edge_out region, normalize in place

    hipMemsetAsync(agg, 0, nb * sizeof(float), stream);
    hipMemsetAsync(stats, 0, 512 * sizeof(float), stream);

    const int ntilesN = (N + 63) / 64;
    node_kernel<<<196, 256, 0, stream>>>(x, Wg, Ws, bs, Wd, bd, g0, g1, srcL, dstL, N, ntilesN);

    const int ntilesE = (E + 63) / 64;
    edge_kernel<<<2048, 256, 0, stream>>>(ea, eidx, Wg + 128 * 64, bg, g0, g1, dstL,
                                          m_out, agg, stats, E, ntilesE);

    node_stats_kernel<<<256, 256, 0, stream>>>(srcL, agg, stats, N);
    finalize_kernel<<<1, 64, 0, stream>>>(stats, gn, bn, ge, be, 1.f / (float)E, 1.f / (float)N);

    edge_norm_kernel<<<4096, 256, 0, stream>>>(m_out, stats, (long)E * 16);
    node_norm_kernel<<<1024, 256, 0, stream>>>(srcL, agg, stats, node_out, (long)N * 16);
}